// Round 12
// baseline (173.709 us; speedup 1.0000x reference)
//
#include <hip/hip_runtime.h>
#include <math.h>

#define HDIM 64
#define VPB 32              // vars per bucket (bucket = dst >> 5)
#define NBR 3200            // partition LDS array sizing (>= NB = 3125)
#define MAXCAP 528          // max edges per bucket (mean 400, +6.4 sigma)
#define PKSHIFT 25          // pk = (vl << 25) | src ; requires src < 2^25
#define PKMASK 0x1FFFFFF
#define SSTR 36             // sums LDS var stride (dwords): 16B-aligned, <=2-way banks

typedef __attribute__((ext_vector_type(8))) short s8v;   // 8 bf16 (4 VGPRs)
typedef __attribute__((ext_vector_type(4))) float f4v;   // MFMA C/D
typedef __attribute__((ext_vector_type(2))) int i2v;     // dwordx2 payload
typedef int i4v __attribute__((vector_size(16)));        // SRSRC (4 SGPRs)

__device__ __forceinline__ int pkbf(float lo, float hi) {   // pack 2 f32 -> 2 bf16
    unsigned ul = __float_as_uint(lo) + 0x8000u;
    unsigned uh = __float_as_uint(hi) + 0x8000u;
    return (int)((ul >> 16) | (uh & 0xffff0000u));
}

// ---------------------------------------------------------------------------
// Pass 1 (partition + cvt fused, disjoint block ranges).
// R12: with XCD-grouped chunk mapping (validated R11, ~+3.4us), the R8
// chunk-size tradeoff is obsolete: a 64B pairs[] line's ~12 sharer-chunks
// now all live on ONE XCD's L2, so small chunks no longer cause cross-XCD
// write amplification. Go back to 4096-edge chunks (NPB=306, 4x the TLP of
// R8's 77 blocks) — R7 proved this shape is fast when write amp is absent
// (its 47us WAS the 42MB amp at ~1TB/s, not the work).
// cvt blocks (bid >= NPB): stream x f32->bf16 on idle CUs (validated R10).
// ---------------------------------------------------------------------------
__global__ __launch_bounds__(1024) void k_part_cvt(
        const int* __restrict__ src, const int* __restrict__ dst,
        int* __restrict__ pairs, int* __restrict__ bcur,
        const float* __restrict__ x, int4* __restrict__ xb,
        int E, int NB, int CAP, int NPB, int n8) {
    __shared__ int hist[NBR], cur[NBR], gb[NBR];
    int t = threadIdx.x;

    if ((int)blockIdx.x >= NPB) {            // ---- cvt blocks ----
        int i = ((int)blockIdx.x - NPB) * 1024 + t;
        if (i < n8) {
            const float4* xp = (const float4*)x + ((size_t)i << 1);
            float4 a = xp[0], bq = xp[1];
            int4 o;
            o.x = pkbf(a.x, a.y);  o.y = pkbf(a.z, a.w);
            o.z = pkbf(bq.x, bq.y); o.w = pkbf(bq.z, bq.w);
            xb[i] = o;
        }
        return;
    }

    // ---- partition blocks: bijective XCD-grouped chunk mapping (m204) ----
    {
        int xg = (int)blockIdx.x & 7, ig = (int)blockIdx.x >> 3;
        int qn = NPB >> 3, rn = NPB & 7;
        int chunk = (xg < rn ? xg * (qn + 1) : rn * (qn + 1) + (xg - rn) * qn) + ig;
        int e0 = chunk << 12;                // 4096 edges per chunk

        for (int j = t; j < NBR; j += 1024) { hist[j] = 0; cur[j] = 0; }
        __syncthreads();

        int pk[4], bb[4];
        #pragma unroll
        for (int k = 0; k < 4; ++k) {
            int e = e0 + (k << 10) + t;
            pk[k] = -1; bb[k] = 0;
            if (e < E) {
                int d = dst[e];
                bb[k] = d >> 5;
                pk[k] = ((d & (VPB - 1)) << PKSHIFT) | src[e];
                atomicAdd(&hist[bb[k]], 1);
            }
        }
        __syncthreads();
        for (int j = t; j < NB; j += 1024) {
            int h = hist[j];
            if (h) gb[j] = j * CAP + atomicAdd(&bcur[j << 4], h);
        }
        __syncthreads();
        #pragma unroll
        for (int k = 0; k < 4; ++k) {
            if (pk[k] != -1) {
                int b = bb[k];
                int r = atomicAdd(&cur[b], 1);
                int g = gb[b] + r;
                if (g < (b + 1) * CAP) pairs[g] = pk[k];
            }
        }
    }
}

// ---------------------------------------------------------------------------
// Pass 2 (byte-identical to R10's validated k_fused): sort + gather + MFMA.
// R12: `nt` reverted — R11 refuted it (kf 46.5->58us, FETCH +8%: L1/L2 were
// supplying ~62% combined hit rate on the 160MB gather demand; nt broke it).
// Single-buffer 16-load forced batch + VMW0 (proven in-register, VGPR 40).
// ---------------------------------------------------------------------------
template<int BF16X>
__global__ __launch_bounds__(128, 4) void k_fused(
        const float* __restrict__ x, const int* __restrict__ xb,
        const int* __restrict__ pairs, const int* __restrict__ bcur,
        const float* __restrict__ W, const float* __restrict__ b,
        const float* __restrict__ gamma, const float* __restrict__ beta,
        float* __restrict__ out, int V, int CAP, int NC) {
    __shared__ int pbuf[MAXCAP];
    __shared__ int sidx[MAXCAP];
    __shared__ int vcnt[VPB], vcur[VPB], voff[VPB];
    __shared__ int sums[2 * 16 * SSTR];      // bf16 sums, wave-private regions
    int t = threadIdx.x;
    int blk = blockIdx.x;
    int base = blk * CAP;
    int cnt = bcur[blk << 4]; if (cnt > CAP) cnt = CAP;

    // SRSRC: num_records in bytes (HW bounds check: OOB load returns 0).
    union { const void* p; int i2[2]; } xa;
    xa.p = BF16X ? (const void*)xb : (const void*)x;
    i4v rsrc;
    rsrc[0] = xa.i2[0];
    rsrc[1] = xa.i2[1];
    rsrc[2] = BF16X ? (NC << 7) : (NC << 8);   // 128B vs 256B per row
    rsrc[3] = 0x00020000;

    if (t < VPB) vcnt[t] = 0;
    __syncthreads();
    for (int e = t; e < cnt; e += 128) {
        int pk = pairs[base + e];
        pbuf[e] = pk;
        atomicAdd(&vcnt[((unsigned)pk) >> PKSHIFT], 1);
    }
    __syncthreads();
    if (t < VPB) {                           // wave 0: shfl exclusive scan (32)
        int c0 = vcnt[t];
        int pre = c0;
        #pragma unroll
        for (int off = 1; off < VPB; off <<= 1) {
            int u = __shfl_up(pre, off, 64);
            if (t >= off) pre += u;
        }
        voff[t] = pre - c0;
        vcur[t] = pre - c0;
    }
    __syncthreads();
    for (int e = t; e < cnt; e += 128) {
        int pk = pbuf[e];
        int slot = atomicAdd(&vcur[((unsigned)pk) >> PKSHIFT], 1);
        sidx[slot] = pk & PKMASK;
    }
    __syncthreads();

    int wv = t >> 6, lane = t & 63, q = lane >> 4, c = lane & 15;
    int sbase = wv * (16 * SSTR);

    // -------- Phase A: gather raw sums (R5-validated per-wave code) ---------
    if (BF16X) {
        for (int jj = 0; jj < 4; ++jj) {
            int lv0 = jj << 2;               // vars lv0..lv0+3 of this wave
            int vb = (wv << 4) + lv0;
            int st[4], dg[4];
            #pragma unroll
            for (int u = 0; u < 4; ++u) { st[u] = voff[vb + u]; dg[u] = vcnt[vb + u]; }
            float ax[4], ay[4], az[4], aw[4];
            #pragma unroll
            for (int u = 0; u < 4; ++u) { ax[u] = 0.f; ay[u] = 0.f; az[u] = 0.f; aw[u] = 0.f; }
            int n = dg[0];
            #pragma unroll
            for (int u = 1; u < 4; ++u) n = dg[u] > n ? dg[u] : n;

            for (int t0 = 0; t0 < n; t0 += 16) {
                unsigned bo[16];
                #pragma unroll
                for (int u = 0; u < 4; ++u)
                    #pragma unroll
                    for (int k = 0; k < 4; ++k) {
                        int m = (u << 2) + k;
                        int ii = t0 + (k << 2) + q;
                        int lim = dg[u] - 1;
                        int iic = ii < lim ? ii : lim;      // LDS-safe index
                        iic = iic > 0 ? iic : 0;
                        unsigned s = (unsigned)sidx[st[u] + iic];
                        unsigned bv = (s << 7) + ((unsigned)c << 3);
                        bo[m] = ii < dg[u] ? bv : 0xFE000000u; // OOB -> 0.0
                    }
                i2v xv[16];
                #pragma unroll
                for (int m = 0; m < 16; ++m)
                    asm volatile("buffer_load_dwordx2 %0, %1, %2, 0 offen"
                                 : "=&v"(xv[m])
                                 : "v"(bo[m]), "s"(rsrc));
                asm volatile("s_waitcnt vmcnt(0)" ::: "memory");
                __builtin_amdgcn_sched_barrier(0);
                #pragma unroll
                for (int u = 0; u < 4; ++u)
                    #pragma unroll
                    for (int k = 0; k < 4; ++k) {
                        int m = (u << 2) + k;
                        unsigned d0 = (unsigned)xv[m][0];
                        unsigned d1 = (unsigned)xv[m][1];
                        ax[u] += __uint_as_float(d0 << 16);
                        ay[u] += __uint_as_float(d0 & 0xffff0000u);
                        az[u] += __uint_as_float(d1 << 16);
                        aw[u] += __uint_as_float(d1 & 0xffff0000u);
                    }
            }
            #pragma unroll
            for (int u = 0; u < 4; ++u) {
                ax[u] += __shfl_xor(ax[u], 16, 64); ay[u] += __shfl_xor(ay[u], 16, 64);
                az[u] += __shfl_xor(az[u], 16, 64); aw[u] += __shfl_xor(aw[u], 16, 64);
                ax[u] += __shfl_xor(ax[u], 32, 64); ay[u] += __shfl_xor(ay[u], 32, 64);
                az[u] += __shfl_xor(az[u], 32, 64); aw[u] += __shfl_xor(aw[u], 32, 64);
            }
            if (q == 0) {                    // lane c writes cols 4c..4c+3 (bf16)
                #pragma unroll
                for (int u = 0; u < 4; ++u) {
                    int o = sbase + (lv0 + u) * SSTR + (c << 1);
                    sums[o]     = pkbf(ax[u], ay[u]);
                    sums[o + 1] = pkbf(az[u], aw[u]);
                }
            }
        }
    } else {
        // f32 fallback: validated 4-var groups, dwordx4 loads
        for (int jj = 0; jj < 4; ++jj) {
            int lv0 = jj << 2;
            int vb = (wv << 4) + lv0;
            int st[4], dg[4];
            #pragma unroll
            for (int u = 0; u < 4; ++u) { st[u] = voff[vb + u]; dg[u] = vcnt[vb + u]; }
            float ax[4], ay[4], az[4], aw[4];
            #pragma unroll
            for (int u = 0; u < 4; ++u) { ax[u] = 0.f; ay[u] = 0.f; az[u] = 0.f; aw[u] = 0.f; }
            int n = dg[0];
            #pragma unroll
            for (int u = 1; u < 4; ++u) n = dg[u] > n ? dg[u] : n;

            for (int t0 = 0; t0 < n; t0 += 16) {
                unsigned bo[16];
                #pragma unroll
                for (int u = 0; u < 4; ++u)
                    #pragma unroll
                    for (int k = 0; k < 4; ++k) {
                        int m = (u << 2) + k;
                        int ii = t0 + (k << 2) + q;
                        int lim = dg[u] - 1;
                        int iic = ii < lim ? ii : lim;
                        iic = iic > 0 ? iic : 0;
                        unsigned s = (unsigned)sidx[st[u] + iic];
                        unsigned bv = (s << 8) + ((unsigned)c << 4);
                        bo[m] = ii < dg[u] ? bv : 0xFE000000u;
                    }
                f4v xv[16];
                #pragma unroll
                for (int m = 0; m < 16; ++m)
                    asm volatile("buffer_load_dwordx4 %0, %1, %2, 0 offen"
                                 : "=&v"(xv[m])
                                 : "v"(bo[m]), "s"(rsrc));
                asm volatile("s_waitcnt vmcnt(0)" ::: "memory");
                __builtin_amdgcn_sched_barrier(0);
                #pragma unroll
                for (int u = 0; u < 4; ++u)
                    #pragma unroll
                    for (int k = 0; k < 4; ++k) {
                        int m = (u << 2) + k;
                        ax[u] += xv[m][0]; ay[u] += xv[m][1];
                        az[u] += xv[m][2]; aw[u] += xv[m][3];
                    }
            }
            #pragma unroll
            for (int u = 0; u < 4; ++u) {
                ax[u] += __shfl_xor(ax[u], 16, 64); ay[u] += __shfl_xor(ay[u], 16, 64);
                az[u] += __shfl_xor(az[u], 16, 64); aw[u] += __shfl_xor(aw[u], 16, 64);
                ax[u] += __shfl_xor(ax[u], 32, 64); ay[u] += __shfl_xor(ay[u], 32, 64);
                az[u] += __shfl_xor(az[u], 32, 64); aw[u] += __shfl_xor(aw[u], 32, 64);
            }
            if (q == 0) {
                #pragma unroll
                for (int u = 0; u < 4; ++u) {
                    int o = sbase + (lv0 + u) * SSTR + (c << 1);
                    sums[o]     = pkbf(ax[u], ay[u]);
                    sums[o + 1] = pkbf(az[u], aw[u]);
                }
            }
        }
    }
    __builtin_amdgcn_wave_barrier();         // wave-private LDS; DS ops in-order

    // -------- Phase B: 8 MFMAs -> 64 outputs x 16 vars ----------------------
    union { int i4[4]; s8v v; } af[4][2];    // A: W[16i+c][h*32+8q .. +7]
    #pragma unroll
    for (int i = 0; i < 4; ++i)
        #pragma unroll
        for (int hh = 0; hh < 2; ++hh) {
            const float* wp = W + (((i << 4) + c) << 6) + (hh << 5) + (q << 3);
            float4 wa = *(const float4*)wp;
            float4 wb = *(const float4*)(wp + 4);
            af[i][hh].i4[0] = pkbf(wa.x, wa.y);
            af[i][hh].i4[1] = pkbf(wa.z, wa.w);
            af[i][hh].i4[2] = pkbf(wb.x, wb.y);
            af[i][hh].i4[3] = pkbf(wb.z, wb.w);
        }
    int so = sbase + c * SSTR + (q << 2);    // B: sums[var c][8q..8q+7] (+16dw: k hi)
    union { int4 i; s8v v; } bf1, bf2;
    bf1.i = *(const int4*)&sums[so];
    bf2.i = *(const int4*)&sums[so + 16];

    f4v acc[4];
    #pragma unroll
    for (int i = 0; i < 4; ++i) {
        acc[i] = (f4v){0.f, 0.f, 0.f, 0.f};
        acc[i] = __builtin_amdgcn_mfma_f32_16x16x32_bf16(af[i][0].v, bf1.v, acc[i], 0, 0, 0);
        acc[i] = __builtin_amdgcn_mfma_f32_16x16x32_bf16(af[i][1].v, bf2.v, acc[i], 0, 0, 0);
    }

    float dv  = (float)vcnt[(wv << 4) + c];  // degree of var c (this wave)
    float inv = 1.0f / (dv + 1e-6f);
    float tb  = dv * inv;
    float hreg[16];
    float s1 = 0.f, s2 = 0.f;
    #pragma unroll
    for (int i = 0; i < 4; ++i) {            // h = relu((W@sum + deg*b)*inv)
        float4 bv = *(const float4*)(b + (i << 4) + (q << 2));
        float hv;
        hv = fmaxf(fmaf(bv.x, tb, acc[i][0] * inv), 0.f); hreg[(i<<2)+0] = hv; s1 += hv; s2 = fmaf(hv, hv, s2);
        hv = fmaxf(fmaf(bv.y, tb, acc[i][1] * inv), 0.f); hreg[(i<<2)+1] = hv; s1 += hv; s2 = fmaf(hv, hv, s2);
        hv = fmaxf(fmaf(bv.z, tb, acc[i][2] * inv), 0.f); hreg[(i<<2)+2] = hv; s1 += hv; s2 = fmaf(hv, hv, s2);
        hv = fmaxf(fmaf(bv.w, tb, acc[i][3] * inv), 0.f); hreg[(i<<2)+3] = hv; s1 += hv; s2 = fmaf(hv, hv, s2);
    }
    s1 += __shfl_xor(s1, 16, 64); s1 += __shfl_xor(s1, 32, 64);
    s2 += __shfl_xor(s2, 16, 64); s2 += __shfl_xor(s2, 32, 64);
    float mu   = s1 * (1.0f / 64.0f);
    float var  = fmaxf(s2 * (1.0f / 64.0f) - mu * mu, 0.0f);
    float rstd = rsqrtf(var + 1e-5f);
    float c0n  = -mu * rstd;

    int v = blk * VPB + (wv << 4) + c;
    if (v < V) {
        #pragma unroll
        for (int i = 0; i < 4; ++i) {
            float4 gv  = *(const float4*)(gamma + (i << 4) + (q << 2));
            float4 btv = *(const float4*)(beta  + (i << 4) + (q << 2));
            float4 o;
            o.x = fmaf(fmaf(hreg[(i<<2)+0], rstd, c0n), gv.x, btv.x);
            o.y = fmaf(fmaf(hreg[(i<<2)+1], rstd, c0n), gv.y, btv.y);
            o.z = fmaf(fmaf(hreg[(i<<2)+2], rstd, c0n), gv.z, btv.z);
            o.w = fmaf(fmaf(hreg[(i<<2)+3], rstd, c0n), gv.w, btv.w);
            *(float4*)(out + ((size_t)v << 6) + (i << 4) + (q << 2)) = o;
        }
    }
}

extern "C" void kernel_launch(void* const* d_in, const int* in_sizes, int n_in,
                              void* d_out, int out_size, void* d_ws, size_t ws_size,
                              hipStream_t stream) {
    const float* x_con = (const float*)d_in[0];
    const int*   src   = (const int*)d_in[1];
    const int*   dst   = (const int*)d_in[2];
    const float* W     = (const float*)d_in[4];
    const float* b     = (const float*)d_in[5];
    const float* gamma = (const float*)d_in[6];
    const float* beta  = (const float*)d_in[7];
    float* out = (float*)d_out;

    int E  = in_sizes[1];
    int NC = in_sizes[0] / HDIM;             // rows of x_con (100000)
    int V  = out_size / HDIM;

    int NB = (V + VPB - 1) / VPB;            // 3125 buckets of 32 vars
    int avg = (E + NB - 1) / NB;             // ~400 edges/bucket
    int CAP = avg + (avg >> 3) + 64;         // +~6.4 sigma headroom
    CAP = (CAP + 15) & ~15;
    if (CAP > MAXCAP) CAP = MAXCAP;

    int NPB = (E + 4095) / 4096;             // partition blocks (306)

    // ws layout: [pairs: NB*CAP int][bcur: NB*16 int][xb: NC*128B bf16 x]
    int* pairs = (int*)d_ws;
    int* bcur  = pairs + (size_t)NB * CAP;
    int* xb    = bcur + (size_t)NB * 16;
    size_t need = ((size_t)NB * CAP + (size_t)NB * 16 + (size_t)NC * 32) * 4;

    hipMemsetAsync(bcur, 0, (size_t)NB * 16 * sizeof(int), stream);
    if (ws_size >= need) {
        int n8 = NC * 8;                     // int4 (8 floats) per thread
        int ncvt = (n8 + 1023) / 1024;       // 782 cvt blocks
        k_part_cvt<<<NPB + ncvt, 1024, 0, stream>>>(src, dst, pairs, bcur,
                                                    x_con, (int4*)xb, E, NB, CAP, NPB, n8);
        k_fused<1><<<NB, 128, 0, stream>>>(x_con, xb, pairs, bcur, W, b, gamma, beta, out, V, CAP, NC);
    } else {
        k_part_cvt<<<NPB, 1024, 0, stream>>>(src, dst, pairs, bcur,
                                             x_con, nullptr, E, NB, CAP, NPB, 0);
        k_fused<0><<<NB, 128, 0, stream>>>(x_con, nullptr, pairs, bcur, W, b, gamma, beta, out, V, CAP, NC);
    }
}

// Round 13
// 158.432 us; speedup vs baseline: 1.0964x; 1.0964x over previous
//
#include <hip/hip_runtime.h>
#include <math.h>

#define HDIM 64
#define VPB 32              // vars per bucket (bucket = dst >> 5)
#define NBR 3200            // partition LDS array sizing (>= NB = 3125)
#define MAXCAP 528          // max edges per bucket (mean 400, +6.4 sigma)
#define PKSHIFT 25          // pk = (vl << 25) | src ; requires src < 2^25
#define PKMASK 0x1FFFFFF
#define SSTR 36             // sums LDS var stride (dwords): 16B-aligned, <=2-way banks

typedef __attribute__((ext_vector_type(8))) short s8v;   // 8 bf16 (4 VGPRs)
typedef __attribute__((ext_vector_type(4))) float f4v;   // MFMA C/D
typedef __attribute__((ext_vector_type(2))) int i2v;     // dwordx2 payload
typedef int i4v __attribute__((vector_size(16)));        // SRSRC (4 SGPRs)

__device__ __forceinline__ int pkbf(float lo, float hi) {   // pack 2 f32 -> 2 bf16
    unsigned ul = __float_as_uint(lo) + 0x8000u;
    unsigned uh = __float_as_uint(hi) + 0x8000u;
    return (int)((ul >> 16) | (uh & 0xffff0000u));
}

// ---------------------------------------------------------------------------
// Pass 1 (R13 = exact R10 revert; best-measured config, 160.1us).
// Partition blocks (0..NPB-1): 16384 edges/block in registers. h =
// 16384/3125 ~= 5.2 records/bucket/block -> pairs[] write amp ~2x. R12
// PROVED amp is set by h alone (atomic-arrival-order allocation), not by
// chunk->XCD mapping, so no swizzle. cvt blocks (bid >= NPB): stream x
// f32->bf16 on the CUs partition leaves idle (saves the serial dispatch).
// ---------------------------------------------------------------------------
__global__ __launch_bounds__(1024) void k_part_cvt(
        const int* __restrict__ src, const int* __restrict__ dst,
        int* __restrict__ pairs, int* __restrict__ bcur,
        const float* __restrict__ x, int4* __restrict__ xb,
        int E, int NB, int CAP, int NPB, int n8) {
    __shared__ int hist[NBR], cur[NBR], gb[NBR];
    int t = threadIdx.x;

    if ((int)blockIdx.x >= NPB) {            // ---- cvt blocks ----
        int i = ((int)blockIdx.x - NPB) * 1024 + t;
        if (i < n8) {
            const float4* xp = (const float4*)x + ((size_t)i << 1);
            float4 a = xp[0], bq = xp[1];
            int4 o;
            o.x = pkbf(a.x, a.y);  o.y = pkbf(a.z, a.w);
            o.z = pkbf(bq.x, bq.y); o.w = pkbf(bq.z, bq.w);
            xb[i] = o;
        }
        return;
    }

    // ---- partition blocks ----
    int e0 = (int)blockIdx.x << 14;          // 16384 edges per block

    for (int j = t; j < NBR; j += 1024) { hist[j] = 0; cur[j] = 0; }
    __syncthreads();

    int pk[16], bb[16];
    #pragma unroll
    for (int k = 0; k < 16; ++k) {
        int e = e0 + (k << 10) + t;
        pk[k] = -1; bb[k] = 0;
        if (e < E) {
            int d = dst[e];
            bb[k] = d >> 5;
            pk[k] = ((d & (VPB - 1)) << PKSHIFT) | src[e];
            atomicAdd(&hist[bb[k]], 1);
        }
    }
    __syncthreads();
    for (int j = t; j < NB; j += 1024) {
        int h = hist[j];
        if (h) gb[j] = j * CAP + atomicAdd(&bcur[j << 4], h);
    }
    __syncthreads();
    #pragma unroll
    for (int k = 0; k < 16; ++k) {
        if (pk[k] != -1) {
            int b = bb[k];
            int r = atomicAdd(&cur[b], 1);
            int g = gb[b] + r;
            if (g < (b + 1) * CAP) pairs[g] = pk[k];
        }
    }
}

// ---------------------------------------------------------------------------
// Pass 2 (byte-identical to R10's validated k_fused): sort + gather + MFMA.
// Structure: VPB 32 -> 128-thread blocks (2 waves), NB=3125 for TLP;
// per-wave: 4-var groups, 16 forced buffer_load_dwordx2 per round (asm,
// stays in registers at VGPR 40), full VMW0 drain, shuffle-reduce, bf16
// sums in LDS, 8 MFMAs, fused deg-norm/ReLU/LN epilogue.
// Established walls: MLP>16 spills (R6), TLP null (R7), 2-deep pipeline
// scratch-demotes (R9), nt hurts L2 (R11). kf = ~46.5us miss-slot bound.
// ---------------------------------------------------------------------------
template<int BF16X>
__global__ __launch_bounds__(128, 4) void k_fused(
        const float* __restrict__ x, const int* __restrict__ xb,
        const int* __restrict__ pairs, const int* __restrict__ bcur,
        const float* __restrict__ W, const float* __restrict__ b,
        const float* __restrict__ gamma, const float* __restrict__ beta,
        float* __restrict__ out, int V, int CAP, int NC) {
    __shared__ int pbuf[MAXCAP];
    __shared__ int sidx[MAXCAP];
    __shared__ int vcnt[VPB], vcur[VPB], voff[VPB];
    __shared__ int sums[2 * 16 * SSTR];      // bf16 sums, wave-private regions
    int t = threadIdx.x;
    int blk = blockIdx.x;
    int base = blk * CAP;
    int cnt = bcur[blk << 4]; if (cnt > CAP) cnt = CAP;

    // SRSRC: num_records in bytes (HW bounds check: OOB load returns 0).
    union { const void* p; int i2[2]; } xa;
    xa.p = BF16X ? (const void*)xb : (const void*)x;
    i4v rsrc;
    rsrc[0] = xa.i2[0];
    rsrc[1] = xa.i2[1];
    rsrc[2] = BF16X ? (NC << 7) : (NC << 8);   // 128B vs 256B per row
    rsrc[3] = 0x00020000;

    if (t < VPB) vcnt[t] = 0;
    __syncthreads();
    for (int e = t; e < cnt; e += 128) {
        int pk = pairs[base + e];
        pbuf[e] = pk;
        atomicAdd(&vcnt[((unsigned)pk) >> PKSHIFT], 1);
    }
    __syncthreads();
    if (t < VPB) {                           // wave 0: shfl exclusive scan (32)
        int c0 = vcnt[t];
        int pre = c0;
        #pragma unroll
        for (int off = 1; off < VPB; off <<= 1) {
            int u = __shfl_up(pre, off, 64);
            if (t >= off) pre += u;
        }
        voff[t] = pre - c0;
        vcur[t] = pre - c0;
    }
    __syncthreads();
    for (int e = t; e < cnt; e += 128) {
        int pk = pbuf[e];
        int slot = atomicAdd(&vcur[((unsigned)pk) >> PKSHIFT], 1);
        sidx[slot] = pk & PKMASK;
    }
    __syncthreads();

    int wv = t >> 6, lane = t & 63, q = lane >> 4, c = lane & 15;
    int sbase = wv * (16 * SSTR);

    // -------- Phase A: gather raw sums (R5-validated per-wave code) ---------
    if (BF16X) {
        for (int jj = 0; jj < 4; ++jj) {
            int lv0 = jj << 2;               // vars lv0..lv0+3 of this wave
            int vb = (wv << 4) + lv0;
            int st[4], dg[4];
            #pragma unroll
            for (int u = 0; u < 4; ++u) { st[u] = voff[vb + u]; dg[u] = vcnt[vb + u]; }
            float ax[4], ay[4], az[4], aw[4];
            #pragma unroll
            for (int u = 0; u < 4; ++u) { ax[u] = 0.f; ay[u] = 0.f; az[u] = 0.f; aw[u] = 0.f; }
            int n = dg[0];
            #pragma unroll
            for (int u = 1; u < 4; ++u) n = dg[u] > n ? dg[u] : n;

            for (int t0 = 0; t0 < n; t0 += 16) {
                unsigned bo[16];
                #pragma unroll
                for (int u = 0; u < 4; ++u)
                    #pragma unroll
                    for (int k = 0; k < 4; ++k) {
                        int m = (u << 2) + k;
                        int ii = t0 + (k << 2) + q;
                        int lim = dg[u] - 1;
                        int iic = ii < lim ? ii : lim;      // LDS-safe index
                        iic = iic > 0 ? iic : 0;
                        unsigned s = (unsigned)sidx[st[u] + iic];
                        unsigned bv = (s << 7) + ((unsigned)c << 3);
                        bo[m] = ii < dg[u] ? bv : 0xFE000000u; // OOB -> 0.0
                    }
                i2v xv[16];
                #pragma unroll
                for (int m = 0; m < 16; ++m)
                    asm volatile("buffer_load_dwordx2 %0, %1, %2, 0 offen"
                                 : "=&v"(xv[m])
                                 : "v"(bo[m]), "s"(rsrc));
                asm volatile("s_waitcnt vmcnt(0)" ::: "memory");
                __builtin_amdgcn_sched_barrier(0);
                #pragma unroll
                for (int u = 0; u < 4; ++u)
                    #pragma unroll
                    for (int k = 0; k < 4; ++k) {
                        int m = (u << 2) + k;
                        unsigned d0 = (unsigned)xv[m][0];
                        unsigned d1 = (unsigned)xv[m][1];
                        ax[u] += __uint_as_float(d0 << 16);
                        ay[u] += __uint_as_float(d0 & 0xffff0000u);
                        az[u] += __uint_as_float(d1 << 16);
                        aw[u] += __uint_as_float(d1 & 0xffff0000u);
                    }
            }
            #pragma unroll
            for (int u = 0; u < 4; ++u) {
                ax[u] += __shfl_xor(ax[u], 16, 64); ay[u] += __shfl_xor(ay[u], 16, 64);
                az[u] += __shfl_xor(az[u], 16, 64); aw[u] += __shfl_xor(aw[u], 16, 64);
                ax[u] += __shfl_xor(ax[u], 32, 64); ay[u] += __shfl_xor(ay[u], 32, 64);
                az[u] += __shfl_xor(az[u], 32, 64); aw[u] += __shfl_xor(aw[u], 32, 64);
            }
            if (q == 0) {                    // lane c writes cols 4c..4c+3 (bf16)
                #pragma unroll
                for (int u = 0; u < 4; ++u) {
                    int o = sbase + (lv0 + u) * SSTR + (c << 1);
                    sums[o]     = pkbf(ax[u], ay[u]);
                    sums[o + 1] = pkbf(az[u], aw[u]);
                }
            }
        }
    } else {
        // f32 fallback: validated 4-var groups, dwordx4 loads
        for (int jj = 0; jj < 4; ++jj) {
            int lv0 = jj << 2;
            int vb = (wv << 4) + lv0;
            int st[4], dg[4];
            #pragma unroll
            for (int u = 0; u < 4; ++u) { st[u] = voff[vb + u]; dg[u] = vcnt[vb + u]; }
            float ax[4], ay[4], az[4], aw[4];
            #pragma unroll
            for (int u = 0; u < 4; ++u) { ax[u] = 0.f; ay[u] = 0.f; az[u] = 0.f; aw[u] = 0.f; }
            int n = dg[0];
            #pragma unroll
            for (int u = 1; u < 4; ++u) n = dg[u] > n ? dg[u] : n;

            for (int t0 = 0; t0 < n; t0 += 16) {
                unsigned bo[16];
                #pragma unroll
                for (int u = 0; u < 4; ++u)
                    #pragma unroll
                    for (int k = 0; k < 4; ++k) {
                        int m = (u << 2) + k;
                        int ii = t0 + (k << 2) + q;
                        int lim = dg[u] - 1;
                        int iic = ii < lim ? ii : lim;
                        iic = iic > 0 ? iic : 0;
                        unsigned s = (unsigned)sidx[st[u] + iic];
                        unsigned bv = (s << 8) + ((unsigned)c << 4);
                        bo[m] = ii < dg[u] ? bv : 0xFE000000u;
                    }
                f4v xv[16];
                #pragma unroll
                for (int m = 0; m < 16; ++m)
                    asm volatile("buffer_load_dwordx4 %0, %1, %2, 0 offen"
                                 : "=&v"(xv[m])
                                 : "v"(bo[m]), "s"(rsrc));
                asm volatile("s_waitcnt vmcnt(0)" ::: "memory");
                __builtin_amdgcn_sched_barrier(0);
                #pragma unroll
                for (int u = 0; u < 4; ++u)
                    #pragma unroll
                    for (int k = 0; k < 4; ++k) {
                        int m = (u << 2) + k;
                        ax[u] += xv[m][0]; ay[u] += xv[m][1];
                        az[u] += xv[m][2]; aw[u] += xv[m][3];
                    }
            }
            #pragma unroll
            for (int u = 0; u < 4; ++u) {
                ax[u] += __shfl_xor(ax[u], 16, 64); ay[u] += __shfl_xor(ay[u], 16, 64);
                az[u] += __shfl_xor(az[u], 16, 64); aw[u] += __shfl_xor(aw[u], 16, 64);
                ax[u] += __shfl_xor(ax[u], 32, 64); ay[u] += __shfl_xor(ay[u], 32, 64);
                az[u] += __shfl_xor(az[u], 32, 64); aw[u] += __shfl_xor(aw[u], 32, 64);
            }
            if (q == 0) {
                #pragma unroll
                for (int u = 0; u < 4; ++u) {
                    int o = sbase + (lv0 + u) * SSTR + (c << 1);
                    sums[o]     = pkbf(ax[u], ay[u]);
                    sums[o + 1] = pkbf(az[u], aw[u]);
                }
            }
        }
    }
    __builtin_amdgcn_wave_barrier();         // wave-private LDS; DS ops in-order

    // -------- Phase B: 8 MFMAs -> 64 outputs x 16 vars ----------------------
    union { int i4[4]; s8v v; } af[4][2];    // A: W[16i+c][h*32+8q .. +7]
    #pragma unroll
    for (int i = 0; i < 4; ++i)
        #pragma unroll
        for (int hh = 0; hh < 2; ++hh) {
            const float* wp = W + (((i << 4) + c) << 6) + (hh << 5) + (q << 3);
            float4 wa = *(const float4*)wp;
            float4 wb = *(const float4*)(wp + 4);
            af[i][hh].i4[0] = pkbf(wa.x, wa.y);
            af[i][hh].i4[1] = pkbf(wa.z, wa.w);
            af[i][hh].i4[2] = pkbf(wb.x, wb.y);
            af[i][hh].i4[3] = pkbf(wb.z, wb.w);
        }
    int so = sbase + c * SSTR + (q << 2);    // B: sums[var c][8q..8q+7] (+16dw: k hi)
    union { int4 i; s8v v; } bf1, bf2;
    bf1.i = *(const int4*)&sums[so];
    bf2.i = *(const int4*)&sums[so + 16];

    f4v acc[4];
    #pragma unroll
    for (int i = 0; i < 4; ++i) {
        acc[i] = (f4v){0.f, 0.f, 0.f, 0.f};
        acc[i] = __builtin_amdgcn_mfma_f32_16x16x32_bf16(af[i][0].v, bf1.v, acc[i], 0, 0, 0);
        acc[i] = __builtin_amdgcn_mfma_f32_16x16x32_bf16(af[i][1].v, bf2.v, acc[i], 0, 0, 0);
    }

    float dv  = (float)vcnt[(wv << 4) + c];  // degree of var c (this wave)
    float inv = 1.0f / (dv + 1e-6f);
    float tb  = dv * inv;
    float hreg[16];
    float s1 = 0.f, s2 = 0.f;
    #pragma unroll
    for (int i = 0; i < 4; ++i) {            // h = relu((W@sum + deg*b)*inv)
        float4 bv = *(const float4*)(b + (i << 4) + (q << 2));
        float hv;
        hv = fmaxf(fmaf(bv.x, tb, acc[i][0] * inv), 0.f); hreg[(i<<2)+0] = hv; s1 += hv; s2 = fmaf(hv, hv, s2);
        hv = fmaxf(fmaf(bv.y, tb, acc[i][1] * inv), 0.f); hreg[(i<<2)+1] = hv; s1 += hv; s2 = fmaf(hv, hv, s2);
        hv = fmaxf(fmaf(bv.z, tb, acc[i][2] * inv), 0.f); hreg[(i<<2)+2] = hv; s1 += hv; s2 = fmaf(hv, hv, s2);
        hv = fmaxf(fmaf(bv.w, tb, acc[i][3] * inv), 0.f); hreg[(i<<2)+3] = hv; s1 += hv; s2 = fmaf(hv, hv, s2);
    }
    s1 += __shfl_xor(s1, 16, 64); s1 += __shfl_xor(s1, 32, 64);
    s2 += __shfl_xor(s2, 16, 64); s2 += __shfl_xor(s2, 32, 64);
    float mu   = s1 * (1.0f / 64.0f);
    float var  = fmaxf(s2 * (1.0f / 64.0f) - mu * mu, 0.0f);
    float rstd = rsqrtf(var + 1e-5f);
    float c0n  = -mu * rstd;

    int v = blk * VPB + (wv << 4) + c;
    if (v < V) {
        #pragma unroll
        for (int i = 0; i < 4; ++i) {
            float4 gv  = *(const float4*)(gamma + (i << 4) + (q << 2));
            float4 btv = *(const float4*)(beta  + (i << 4) + (q << 2));
            float4 o;
            o.x = fmaf(fmaf(hreg[(i<<2)+0], rstd, c0n), gv.x, btv.x);
            o.y = fmaf(fmaf(hreg[(i<<2)+1], rstd, c0n), gv.y, btv.y);
            o.z = fmaf(fmaf(hreg[(i<<2)+2], rstd, c0n), gv.z, btv.z);
            o.w = fmaf(fmaf(hreg[(i<<2)+3], rstd, c0n), gv.w, btv.w);
            *(float4*)(out + ((size_t)v << 6) + (i << 4) + (q << 2)) = o;
        }
    }
}

extern "C" void kernel_launch(void* const* d_in, const int* in_sizes, int n_in,
                              void* d_out, int out_size, void* d_ws, size_t ws_size,
                              hipStream_t stream) {
    const float* x_con = (const float*)d_in[0];
    const int*   src   = (const int*)d_in[1];
    const int*   dst   = (const int*)d_in[2];
    const float* W     = (const float*)d_in[4];
    const float* b     = (const float*)d_in[5];
    const float* gamma = (const float*)d_in[6];
    const float* beta  = (const float*)d_in[7];
    float* out = (float*)d_out;

    int E  = in_sizes[1];
    int NC = in_sizes[0] / HDIM;             // rows of x_con (100000)
    int V  = out_size / HDIM;

    int NB = (V + VPB - 1) / VPB;            // 3125 buckets of 32 vars
    int avg = (E + NB - 1) / NB;             // ~400 edges/bucket
    int CAP = avg + (avg >> 3) + 64;         // +~6.4 sigma headroom
    CAP = (CAP + 15) & ~15;
    if (CAP > MAXCAP) CAP = MAXCAP;

    int NPB = (E + 16383) / 16384;           // partition blocks (77)

    // ws layout: [pairs: NB*CAP int][bcur: NB*16 int][xb: NC*128B bf16 x]
    int* pairs = (int*)d_ws;
    int* bcur  = pairs + (size_t)NB * CAP;
    int* xb    = bcur + (size_t)NB * 16;
    size_t need = ((size_t)NB * CAP + (size_t)NB * 16 + (size_t)NC * 32) * 4;

    hipMemsetAsync(bcur, 0, (size_t)NB * 16 * sizeof(int), stream);
    if (ws_size >= need) {
        int n8 = NC * 8;                     // int4 (8 floats) per thread
        int ncvt = (n8 + 1023) / 1024;       // 782 cvt blocks
        k_part_cvt<<<NPB + ncvt, 1024, 0, stream>>>(src, dst, pairs, bcur,
                                                    x_con, (int4*)xb, E, NB, CAP, NPB, n8);
        k_fused<1><<<NB, 128, 0, stream>>>(x_con, xb, pairs, bcur, W, b, gamma, beta, out, V, CAP, NC);
    } else {
        k_part_cvt<<<NPB, 1024, 0, stream>>>(src, dst, pairs, bcur,
                                             x_con, nullptr, E, NB, CAP, NPB, 0);
        k_fused<0><<<NB, 128, 0, stream>>>(x_con, nullptr, pairs, bcur, W, b, gamma, beta, out, V, CAP, NC);
    }
}